// Round 12
// baseline (639.187 us; speedup 1.0000x reference)
//
#include <hip/hip_runtime.h>
#include <cstdint>
#include <cstddef>

#define Bn 128
#define Ln 1024
#define Fn 128
#define Hn 64
#define NGn 256           // 4*H
#define NCn 16
#define IN_DIM (Hn + Fn*Hn)   // 8256

typedef float    f32x4 __attribute__((ext_vector_type(4)));
typedef float    f32x2 __attribute__((ext_vector_type(2)));
typedef _Float16 f16x8 __attribute__((ext_vector_type(8)));
typedef _Float16 f16x2 __attribute__((ext_vector_type(2)));

union U8 { f16x8 v; f16x2 p[4]; };
struct SlabR { f16x8 w[8]; f32x2 wb; };   // 32 + 2 VGPRs

__device__ __forceinline__ float fsigm(float x) {
    return __fdividef(1.0f, 1.0f + __expf(-x));
}
__device__ __forceinline__ float ftanh(float x) {
    float e = __expf(2.0f * x);
    return 1.0f - __fdividef(2.0f, e + 1.0f);
}
__device__ __forceinline__ float sigm_slow(float x) { return 1.0f / (1.0f + expf(-x)); }

template<int P>
__device__ __forceinline__ float qperm(float v) {
    return __int_as_float(__builtin_amdgcn_mov_dpp(__float_as_int(v), P, 0xf, 0xf, true));
}
#define QRED(A) do { A += qperm<0xB1>(A); A += qperm<0x4E>(A); } while (0)

#if __has_builtin(__builtin_amdgcn_fdot2)
#define DOT2(WP, HP, ACC) __builtin_amdgcn_fdot2((WP), (HP), (ACC), false)
#else
#define DOT2(WP, HP, ACC) fmaf((float)(WP)[0], (float)(HP)[0], \
                               fmaf((float)(WP)[1], (float)(HP)[1], (ACC)))
#endif

// thread tid: q = tid&3 (k-quarter AND own-gate), u = (tid>>6)*16 + ((tid>>2)&15)
// Gw[((f*8 + c)*256 + tid)*8 + e] = (f16) W_gates[f][(c>>1)*64 + u][1 + 16q + 8*(c&1) + e]
// Gwb[f*256 + tid] = (W_gates[f][q*64+u][0], b_gates[f][q*64+u])
__global__ __launch_bounds__(256)
void prep_f16(const float* __restrict__ Wg, const float* __restrict__ bg,
              _Float16* __restrict__ Gw, f32x2* __restrict__ Gwb)
{
    const int f = blockIdx.x, tid = threadIdx.x;
    const int q = tid & 3;
    const int u = (tid >> 6) * 16 + ((tid >> 2) & 15);
    {
        const float* srcq = Wg + ((size_t)f * NGn + q * 64 + u) * 65;
        f32x2 wb; wb[0] = srcq[0]; wb[1] = bg[f * NGn + q * 64 + u];
        Gwb[f * NGn + tid] = wb;
    }
#pragma unroll
    for (int c = 0; c < 8; ++c) {
        const int r = c >> 1;
        const float* src = Wg + ((size_t)f * NGn + r * 64 + u) * 65;
        f16x8 v;
#pragma unroll
        for (int e = 0; e < 8; ++e) v[e] = (_Float16)src[1 + 16 * q + 8 * (c & 1) + e];
        *(f16x8*)(Gw + (((size_t)f * 8 + c) * NGn + tid) * 8) = v;
    }
}

// One step consuming register slab CUR (loaded last step); loads step j+1's
// slab into NXT with PLAIN loads. sched_barrier(0) right after the issue
// forbids the scheduler from SINKING the loads toward their use (rule that
// defeated rounds 7/11); the pin asm at the tail bounds them from below, so
// the compiler's own counted vmcnt lands after ~400 cycles of dot/transc
// work — latency covered, and all accounting stays compiler-visible.
#define STEPD(CUR, NXT)                                                         \
    {                                                                           \
        /* h fragments for this step (h-writes certified by prev B2) */         \
        U8 ha, hb;                                                              \
        {                                                                       \
            const f16x8* hp_ = (const f16x8*)(h16 + (mj << 6) + (q << 4));      \
            ha.v = hp_[0]; hb.v = hp_[1];                                       \
        }                                                                       \
        /* plain W(j+1) loads issued early */                                   \
        {                                                                       \
            const _Float16* wbp_ = Gw + ((size_t)m1 << 14) + (tid << 3);        \
            _Pragma("unroll")                                                   \
            for (int c_ = 0; c_ < 8; ++c_)                                      \
                NXT.w[c_] = *(const f16x8*)(wbp_ + (c_ << 11));                 \
            NXT.wb = Gwb[(m1 << 8) + tid];                                      \
        }                                                                       \
        __builtin_amdgcn_sched_barrier(0);   /* loads may NOT sink below */     \
        const int jpf_ = (j + 2 < len) ? j + 2 : len - 1;                       \
        const f32x4 pn_ = pk_s[jpf_];                                           \
        float a0_ = 0.f, a1_ = 0.f, a2_ = 0.f, a3_ = 0.f;                       \
        {                                                                       \
            U8 w0_, w1_;                                                        \
            w0_.v = CUR.w[0]; w1_.v = CUR.w[1];                                 \
            _Pragma("unroll")                                                   \
            for (int e_ = 0; e_ < 4; ++e_) { a0_ = DOT2(w0_.p[e_], ha.p[e_], a0_); a0_ = DOT2(w1_.p[e_], hb.p[e_], a0_); } \
            w0_.v = CUR.w[2]; w1_.v = CUR.w[3];                                 \
            _Pragma("unroll")                                                   \
            for (int e_ = 0; e_ < 4; ++e_) { a1_ = DOT2(w0_.p[e_], ha.p[e_], a1_); a1_ = DOT2(w1_.p[e_], hb.p[e_], a1_); } \
            w0_.v = CUR.w[4]; w1_.v = CUR.w[5];                                 \
            _Pragma("unroll")                                                   \
            for (int e_ = 0; e_ < 4; ++e_) { a2_ = DOT2(w0_.p[e_], ha.p[e_], a2_); a2_ = DOT2(w1_.p[e_], hb.p[e_], a2_); } \
            w0_.v = CUR.w[6]; w1_.v = CUR.w[7];                                 \
            _Pragma("unroll")                                                   \
            for (int e_ = 0; e_ < 4; ++e_) { a3_ = DOT2(w0_.p[e_], ha.p[e_], a3_); a3_ = DOT2(w1_.p[e_], hb.p[e_], a3_); } \
        }                                                                       \
        const float own_ = fmaf(CUR.wb[0], xj, CUR.wb[1]);                      \
        a0_ = fmaf(a0_, dj, (q == 0) ? own_ : 0.0f);                            \
        a1_ = fmaf(a1_, dj, (q == 1) ? own_ : 0.0f);                            \
        a2_ = fmaf(a2_, dj, (q == 2) ? own_ : 0.0f);                            \
        a3_ = fmaf(a3_, dj, (q == 3) ? own_ : 0.0f);                            \
        QRED(a0_); QRED(a1_); QRED(a2_); QRED(a3_);                             \
        const float cn_ = fmaf(fsigm(a1_), cu, fsigm(a0_) * ftanh(a3_));        \
        cu = cn_;                                                               \
        const float ho_ = fsigm(a2_) * ftanh(cn_);                              \
        const float hs_ = __int_as_float(__builtin_amdgcn_ds_swizzle(           \
                              __float_as_int(ho_), 0x101F));  /* lane^4 */      \
        const int mwr_ = mj;                                                    \
        mj = m1; xj = x1; dj = d1;                                              \
        m1 = __float_as_int(pn_[2]); x1 = pn_[0]; d1 = pn_[1];                  \
        __builtin_amdgcn_s_barrier();   /* B1: all h reads done (consumed) */   \
        if ((l & 7) == 0) {                                                     \
            f16x2 pr_; pr_[0] = (_Float16)ho_; pr_[1] = (_Float16)hs_;          \
            *(f16x2*)(h16 + (mwr_ << 6) + u) = pr_;                             \
        }                                                                       \
        asm volatile("s_waitcnt lgkmcnt(0)" ::: "memory");                      \
        /* pin: W(j+1) must be materialized here (counted vmcnt, ~0 stall) */   \
        asm volatile("" : "+v"(NXT.w[0]), "+v"(NXT.w[1]), "+v"(NXT.w[2]),       \
                          "+v"(NXT.w[3]), "+v"(NXT.w[4]), "+v"(NXT.w[5]),       \
                          "+v"(NXT.w[6]), "+v"(NXT.w[7]), "+v"(NXT.wb));        \
        __builtin_amdgcn_s_barrier();   /* B2: h writes visible */              \
    }

__global__ __launch_bounds__(256, 1)
void lstm_pre(const float* __restrict__ X, const int* __restrict__ lengths,
              const _Float16* __restrict__ Gw, const f32x2* __restrict__ Gwb,
              const float* __restrict__ wdec, const float* __restrict__ bdec,
              const float* __restrict__ Wo, const float* __restrict__ bo,
              float* __restrict__ out)
{
    __shared__ __align__(16) _Float16 h16[Fn * Hn];   // 16 KB f16 h state
    __shared__ __align__(16) f32x4 pk_s[Ln];          // 16 KB {x, dec, m_bits, 0}
    __shared__ float c_s[Hn];
    __shared__ float wd_s[Fn], bd_s[Fn];
    __shared__ float red_lds[4 * NCn];
    __shared__ float logit_lds[NCn];

    const int b   = blockIdx.x;
    const int tid = threadIdx.x;
    const int l   = tid & 63;
    const int w   = tid >> 6;
    const int q   = l & 3;              // k-quarter AND own-gate
    const int u   = w * 16 + (l >> 2);  // hidden unit owned by this quad

    const float* mrow = X + ((size_t)b * 4 + 1) * Ln;
    const float* xrow = X + ((size_t)b * 4 + 2) * Ln;
    const float* drow = X + ((size_t)b * 4 + 3) * Ln;

    {
        f16x8 hz;
#pragma unroll
        for (int e = 0; e < 8; ++e) hz[e] = (_Float16)0.0f;
        for (int i = tid; i < (Fn * Hn / 8); i += 256) ((f16x8*)h16)[i] = hz;
    }
    if (tid < Fn) { wd_s[tid] = wdec[tid]; bd_s[tid] = bdec[tid]; }
    __syncthreads();

    // precompute packed per-step params: {x, dec, m} (one broadcast b128/step)
    for (int jj = tid; jj < Ln; jj += 256) {
        const int   m  = (int)mrow[jj];
        const float dec = __expf(-fmaxf(0.0f, fmaf(wd_s[m], drow[jj], bd_s[m])));
        f32x4 t; t[0] = xrow[jj]; t[1] = dec; t[2] = __int_as_float(m); t[3] = 0.0f;
        pk_s[jj] = t;
    }
    __syncthreads();

    int len = lengths[b];
    if (len > Ln) len = Ln;

    float cu = 0.0f;   // c[u], replicated across the quad

    if (len > 0) {
        f32x4 p0 = pk_s[0];
        f32x4 p1 = pk_s[(1 < len) ? 1 : 0];
        int   mj = __float_as_int(p0[2]);
        float xj = p0[0], dj = p0[1];
        int   m1 = __float_as_int(p1[2]);
        float x1 = p1[0], d1 = p1[1];

        SlabR sA, sB;
        {   // prologue: load W(0) (plain; first consumption forces the wait)
            const _Float16* wbp = Gw + ((size_t)mj << 14) + (tid << 3);
#pragma unroll
            for (int c = 0; c < 8; ++c)
                sA.w[c] = *(const f16x8*)(wbp + (c << 11));
            sA.wb = Gwb[(mj << 8) + tid];
        }

        int j = 0;
        for (;;) {
            STEPD(sA, sB); if (++j >= len) break;
            STEPD(sB, sA); if (++j >= len) break;
        }
    }
    if (q == 0) c_s[u] = cu;
    __syncthreads();

    // ---- output head: logits = W_out @ [c; h.flatten()] + b_out, softmax ----
    float p[NCn];
#pragma unroll
    for (int c = 0; c < NCn; ++c) p[c] = 0.0f;
    for (int i = tid; i < IN_DIM; i += 256) {
        const float fv = (i < Hn) ? c_s[i] : (float)h16[i - Hn];
#pragma unroll
        for (int c = 0; c < NCn; ++c)
            p[c] = fmaf(Wo[(size_t)c * IN_DIM + i], fv, p[c]);
    }
#pragma unroll
    for (int c = 0; c < NCn; ++c) {
        float v = p[c];
#pragma unroll
        for (int off = 32; off > 0; off >>= 1) v += __shfl_down(v, off, 64);
        if (l == 0) red_lds[w * NCn + c] = v;
    }
    __syncthreads();
    if (tid < NCn) {
        logit_lds[tid] = red_lds[tid] + red_lds[NCn + tid] +
                         red_lds[2 * NCn + tid] + red_lds[3 * NCn + tid] + bo[tid];
    }
    __syncthreads();
    if (tid == 0) {
        float mx = logit_lds[0];
        for (int c = 1; c < NCn; ++c) mx = fmaxf(mx, logit_lds[c]);
        float e[NCn], sm = 0.0f;
        for (int c = 0; c < NCn; ++c) { e[c] = expf(logit_lds[c] - mx); sm += e[c]; }
        const float inv = 1.0f / sm;
        for (int c = 0; c < NCn; ++c) out[(size_t)b * NCn + c] = e[c] * inv;
    }
}

// ---- fallback (no workspace): raw f32 weights each step ----
__global__ __launch_bounds__(256)
void lstm_fallback(const float* __restrict__ X, const int* __restrict__ lengths,
                   const float* __restrict__ Wg, const float* __restrict__ bg,
                   const float* __restrict__ wdec, const float* __restrict__ bdec,
                   const float* __restrict__ Wo, const float* __restrict__ bo,
                   float* __restrict__ out)
{
    __shared__ __align__(16) float h_lds[Fn * Hn];
    __shared__ float c_lds[Hn];
    __shared__ int   m_lds[Ln];
    __shared__ float x_lds[Ln];
    __shared__ float d_lds[Ln];
    __shared__ float wd_lds[Fn], bd_lds[Fn];
    __shared__ float red_lds[4 * NCn];
    __shared__ float logit_lds[NCn];

    const int b   = blockIdx.x;
    const int tid = threadIdx.x;
    const int l   = tid & 63;
    const int w   = tid >> 6;
    const int q   = l & 3;
    const int u   = w * 16 + (l >> 2);

    const float* mrow = X + ((size_t)b * 4 + 1) * Ln;
    const float* xrow = X + ((size_t)b * 4 + 2) * Ln;
    const float* drow = X + ((size_t)b * 4 + 3) * Ln;

    for (int i = tid; i < Fn * Hn; i += 256) h_lds[i] = 0.0f;
    if (tid < Hn) c_lds[tid] = 0.0f;
    if (tid < Fn) { wd_lds[tid] = wdec[tid]; bd_lds[tid] = bdec[tid]; }
    for (int i = tid; i < Ln; i += 256) {
        m_lds[i] = (int)mrow[i];
        x_lds[i] = xrow[i];
        d_lds[i] = drow[i];
    }
    __syncthreads();

    int len = lengths[b];
    if (len > Ln) len = Ln;
    const int g_raw = q * 64 + u;

    for (int j = 0; j < len; ++j) {
        const int   mj = m_lds[j];
        const float xj = x_lds[j];
        const float dj = d_lds[j];
        const float dec = expf(-fmaxf(0.0f, fmaf(wd_lds[mj], dj, bd_lds[mj])));
        const float4* hp = (const float4*)(h_lds + mj * Hn);
        const float* row = Wg + ((size_t)mj * NGn + g_raw) * 65;
        float acc = fmaf(row[0], xj, bg[mj * NGn + g_raw]);
        float a0 = 0.f, a1 = 0.f, a2 = 0.f, a3 = 0.f;
#pragma unroll
        for (int k4 = 0; k4 < 16; ++k4) {
            float4 hv = hp[k4];
            a0 = fmaf(row[1 + 4*k4 + 0], hv.x, a0);
            a1 = fmaf(row[1 + 4*k4 + 1], hv.y, a1);
            a2 = fmaf(row[1 + 4*k4 + 2], hv.z, a2);
            a3 = fmaf(row[1 + 4*k4 + 3], hv.w, a3);
        }
        acc = fmaf(dec, (a0 + a1) + (a2 + a3), acc);
        const int base = l & ~3;
        const float gi = __shfl(acc, base + 0, 64);
        const float gf = __shfl(acc, base + 1, 64);
        const float go = __shfl(acc, base + 2, 64);
        const float gc = __shfl(acc, base + 3, 64);
        __syncthreads();
        const float c_new = fmaf(sigm_slow(gf), c_lds[u], sigm_slow(gi) * tanhf(gc));
        if (q == 0) {
            c_lds[u] = c_new;
            h_lds[mj * Hn + u] = sigm_slow(go) * tanhf(c_new);
        }
        __syncthreads();
    }

    float p[NCn];
#pragma unroll
    for (int c = 0; c < NCn; ++c) p[c] = 0.0f;
    for (int i = tid; i < IN_DIM; i += 256) {
        const float fv = (i < Hn) ? c_lds[i] : h_lds[i - Hn];
#pragma unroll
        for (int c = 0; c < NCn; ++c)
            p[c] = fmaf(Wo[(size_t)c * IN_DIM + i], fv, p[c]);
    }
#pragma unroll
    for (int c = 0; c < NCn; ++c) {
        float v = p[c];
#pragma unroll
        for (int off = 32; off > 0; off >>= 1) v += __shfl_down(v, off, 64);
        if (l == 0) red_lds[w * NCn + c] = v;
    }
    __syncthreads();
    if (tid < NCn) {
        logit_lds[tid] = red_lds[tid] + red_lds[NCn + tid] +
                         red_lds[2 * NCn + tid] + red_lds[3 * NCn + tid] + bo[tid];
    }
    __syncthreads();
    if (tid == 0) {
        float mx = logit_lds[0];
        for (int c = 1; c < NCn; ++c) mx = fmaxf(mx, logit_lds[c]);
        float e[NCn], s = 0.0f;
        for (int c = 0; c < NCn; ++c) { e[c] = expf(logit_lds[c] - mx); s += e[c]; }
        const float inv = 1.0f / s;
        for (int c = 0; c < NCn; ++c) out[(size_t)b * NCn + c] = e[c] * inv;
    }
}

extern "C" void kernel_launch(void* const* d_in, const int* in_sizes, int n_in,
                              void* d_out, int out_size, void* d_ws, size_t ws_size,
                              hipStream_t stream)
{
    const float* X      = (const float*)d_in[0];
    const int*   len    = (const int*)  d_in[1];
    const float* Wg     = (const float*)d_in[2];
    const float* bg     = (const float*)d_in[3];
    const float* wdec   = (const float*)d_in[4];
    const float* bdec   = (const float*)d_in[5];
    const float* Wo     = (const float*)d_in[6];
    const float* bo     = (const float*)d_in[7];
    float*       out    = (float*)d_out;

    const size_t gw_bytes  = (size_t)Fn * 8 * NGn * 8 * sizeof(_Float16); // 4,194,304
    const size_t gwb_bytes = (size_t)Fn * NGn * sizeof(f32x2);            // 262,144
    const size_t need      = gw_bytes + gwb_bytes;

    if (ws_size >= need) {
        _Float16* Gw  = (_Float16*)d_ws;
        f32x2*    Gwb = (f32x2*)((char*)d_ws + gw_bytes);
        prep_f16<<<Fn, 256, 0, stream>>>(Wg, bg, Gw, Gwb);
        lstm_pre<<<Bn, 256, 0, stream>>>(X, len, Gw, Gwb,
                                         wdec, bdec, Wo, bo, out);
    } else {
        lstm_fallback<<<Bn, 256, 0, stream>>>(X, len, Wg, bg,
                                              wdec, bdec, Wo, bo, out);
    }
}

// Round 13
// 616.889 us; speedup vs baseline: 1.0361x; 1.0361x over previous
//
#include <hip/hip_runtime.h>
#include <cstdint>
#include <cstddef>

#define Bn 128
#define Ln 1024
#define Fn 128
#define Hn 64
#define NGn 256           // 4*H
#define NCn 16
#define IN_DIM (Hn + Fn*Hn)   // 8256
#define WMAX 4            // window width = waves per block

typedef float    f32x4 __attribute__((ext_vector_type(4)));
typedef float    f32x2 __attribute__((ext_vector_type(2)));
typedef _Float16 f16x8 __attribute__((ext_vector_type(8)));
typedef _Float16 f16x2 __attribute__((ext_vector_type(2)));

union U8 { f16x8 v; f16x2 p[4]; };

__device__ __forceinline__ float fsigm(float x) {
    return __fdividef(1.0f, 1.0f + __expf(-x));
}
__device__ __forceinline__ float ftanh(float x) {
    float e = __expf(2.0f * x);
    return 1.0f - __fdividef(2.0f, e + 1.0f);
}
__device__ __forceinline__ float sigm_slow(float x) { return 1.0f / (1.0f + expf(-x)); }

#if __has_builtin(__builtin_amdgcn_fdot2)
#define DOT2(WP, HP, ACC) __builtin_amdgcn_fdot2((WP), (HP), (ACC), false)
#else
#define DOT2(WP, HP, ACC) fmaf((float)(WP)[0], (float)(HP)[0], \
                               fmaf((float)(WP)[1], (float)(HP)[1], (ACC)))
#endif

// Lane-local-gates layout (lane = hidden unit u, all 4 gates in-lane):
//   Gw[m*2048 + c*64 + u] (f16x8) = W_gates[m][g*64+u][1 + ko*8 .. +8], c = g*8+ko
//   (instruction c is a coalesced 1KB wave load: lanes u adjacent)
//   Gwb[m*512 + u*8 + g*2 + {0,1}] = { W_gates[m][g*64+u][0], b_gates[m][g*64+u] }
__global__ __launch_bounds__(256)
void prep_f16(const float* __restrict__ Wg, const float* __restrict__ bg,
              f16x8* __restrict__ Gw, float* __restrict__ Gwb)
{
    const int m = blockIdx.x, t = threadIdx.x;
    for (int e = t; e < 2048; e += 256) {
        const int c  = e >> 6, u = e & 63;
        const int g  = c >> 3, ko = c & 7;
        const float* src = Wg + ((size_t)m * NGn + g * 64 + u) * 65 + 1 + ko * 8;
        f16x8 v;
#pragma unroll
        for (int k = 0; k < 8; ++k) v[k] = (_Float16)src[k];
        Gw[(size_t)m * 2048 + e] = v;
    }
    for (int e = t; e < 512; e += 256) {
        const int u = e >> 3, idx = e & 7, g = idx >> 1;
        const size_t row = (size_t)m * NGn + g * 64 + u;
        Gwb[(size_t)m * 512 + e] = (idx & 1) ? bg[row] : Wg[row * 65];
    }
}

__global__ __launch_bounds__(256, 1)
void lstm_pre(const float* __restrict__ X, const int* __restrict__ lengths,
              const f16x8* __restrict__ Gw, const float* __restrict__ Gwb,
              const float* __restrict__ wdec, const float* __restrict__ bdec,
              const float* __restrict__ Wo, const float* __restrict__ bo,
              float* __restrict__ out)
{
    __shared__ __align__(16) _Float16 h16[Fn * Hn];   // 16 KB f16 h state
    __shared__ __align__(16) f32x4 pk_s[Ln];          // 16 KB {x, dec, m_bits, 0}
    __shared__ __align__(16) f32x4 glds[WMAX * Hn];   // 4 KB gate buffer
    __shared__ unsigned char sz_s[Ln];                // 1 KB window sizes
    __shared__ float c_s[Hn];
    __shared__ float wd_s[Fn], bd_s[Fn];
    __shared__ float red_lds[4 * NCn];
    __shared__ float logit_lds[NCn];

    const int b   = blockIdx.x;
    const int tid = threadIdx.x;
    const int l   = tid & 63;          // lane == hidden unit u
    const int w   = tid >> 6;          // wave == window slot

    const float* mrow = X + ((size_t)b * 4 + 1) * Ln;
    const float* xrow = X + ((size_t)b * 4 + 2) * Ln;
    const float* drow = X + ((size_t)b * 4 + 3) * Ln;

    {
        f16x8 hz;
#pragma unroll
        for (int e = 0; e < 8; ++e) hz[e] = (_Float16)0.0f;
        for (int i = tid; i < (Fn * Hn / 8); i += 256) ((f16x8*)h16)[i] = hz;
    }
    if (tid < Fn) { wd_s[tid] = wdec[tid]; bd_s[tid] = bdec[tid]; }
    __syncthreads();

    // per-step params {x, dec, m}
    for (int jj = tid; jj < Ln; jj += 256) {
        const int   m   = (int)mrow[jj];
        const float dec = __expf(-fmaxf(0.0f, fmaf(wd_s[m], drow[jj], bd_s[m])));
        f32x4 t; t[0] = xrow[jj]; t[1] = dec; t[2] = __int_as_float(m); t[3] = 0.0f;
        pk_s[jj] = t;
    }
    __syncthreads();

    // sz_s[j] = longest pairwise-distinct-m run from j, capped at WMAX
    for (int j0 = tid; j0 < Ln; j0 += 256) {
        int mm[WMAX];
        mm[0] = __float_as_int(pk_s[j0][2]);
        int s = 1;
#pragma unroll
        for (int i = 1; i < WMAX; ++i) {
            if (j0 + i < Ln) {
                const int mi = __float_as_int(pk_s[j0 + i][2]);
                bool dup = false;
#pragma unroll
                for (int t2 = 0; t2 < i; ++t2) dup = dup || (mm[t2] == mi);
                mm[i] = mi;
                if (!dup && s == i) s = i + 1;
            }
        }
        sz_s[j0] = (unsigned char)s;
    }
    __syncthreads();

    int len = lengths[b];
    if (len > Ln) len = Ln;

    float cu = 0.0f;   // c[l], identical across all 4 waves

    int jg = 0;
    while (jg < len) {
        int szc = (int)sz_s[jg];
        const int rem = len - jg;
        if (szc > rem) szc = rem;

        const bool active = (w < szc);
        int mw = 0;
        if (active) {
            const int   j  = jg + w;
            const f32x4 pj = pk_s[j];
            const int   m  = __float_as_int(pj[2]);
            mw = m;

            // per-lane W row-group: 32 coalesced f16x8 loads (L2-resident)
            const f16x8* wp = Gw + (size_t)m * 2048 + l;
            f16x8 wreg[32];
#pragma unroll
            for (int c = 0; c < 32; ++c) wreg[c] = wp[c * 64];

            // wx/bias: 8 floats per lane
            const f32x4* wbp = (const f32x4*)(Gwb + (size_t)m * 512 + (l << 3));
            const f32x4 wb01 = wbp[0];   // wx_i, b_i, wx_f, b_f
            const f32x4 wb23 = wbp[1];   // wx_o, b_o, wx_c, b_c

            // h row m: 8 broadcast b128 reads (all lanes same address)
            U8 hrow[8];
            const f16x8* hp = (const f16x8*)(h16 + (m << 6));
#pragma unroll
            for (int c = 0; c < 8; ++c) hrow[c].v = hp[c];

            float a0 = 0.f, a1 = 0.f, a2 = 0.f, a3 = 0.f;
#pragma unroll
            for (int c = 0; c < 8; ++c) {
                U8 w0, w1, w2, w3;
                w0.v = wreg[c]; w1.v = wreg[8 + c];
                w2.v = wreg[16 + c]; w3.v = wreg[24 + c];
#pragma unroll
                for (int e = 0; e < 4; ++e) {
                    a0 = DOT2(w0.p[e], hrow[c].p[e], a0);
                    a1 = DOT2(w1.p[e], hrow[c].p[e], a1);
                    a2 = DOT2(w2.p[e], hrow[c].p[e], a2);
                    a3 = DOT2(w3.p[e], hrow[c].p[e], a3);
                }
            }
            const float x = pj[0], dec = pj[1];
            f32x4 g4;
            g4[0] = fmaf(a0, dec, fmaf(wb01[0], x, wb01[1]));   // i
            g4[1] = fmaf(a1, dec, fmaf(wb01[2], x, wb01[3]));   // f
            g4[2] = fmaf(a2, dec, fmaf(wb23[0], x, wb23[1]));   // o
            g4[3] = fmaf(a3, dec, fmaf(wb23[2], x, wb23[3]));   // c
            glds[(w << 6) + l] = g4;
        }
        __syncthreads();   // B1: gates visible; all h reads of window done

        // elementwise c-scan, redundantly in every wave (keeps cu coherent)
        float hval = 0.0f;
#pragma unroll
        for (int s = 0; s < WMAX; ++s) {
            if (s < szc) {
                const f32x4 g = glds[(s << 6) + l];
                const float cn = fmaf(fsigm(g[1]), cu, fsigm(g[0]) * ftanh(g[3]));
                cu = cn;
                const float hv = fsigm(g[2]) * ftanh(cn);
                if (s == w) hval = hv;
            }
        }
        if (active) h16[(mw << 6) + l] = (_Float16)hval;   // 128B contiguous
        __syncthreads();   // B2: h writes visible
        jg += szc;
    }
    if (w == 0) c_s[l] = cu;
    __syncthreads();

    // ---- output head: logits = W_out @ [c; h.flatten()] + b_out, softmax ----
    float p[NCn];
#pragma unroll
    for (int c = 0; c < NCn; ++c) p[c] = 0.0f;
    for (int i = tid; i < IN_DIM; i += 256) {
        const float fv = (i < Hn) ? c_s[i] : (float)h16[i - Hn];
#pragma unroll
        for (int c = 0; c < NCn; ++c)
            p[c] = fmaf(Wo[(size_t)c * IN_DIM + i], fv, p[c]);
    }
#pragma unroll
    for (int c = 0; c < NCn; ++c) {
        float v = p[c];
#pragma unroll
        for (int off = 32; off > 0; off >>= 1) v += __shfl_down(v, off, 64);
        if (l == 0) red_lds[w * NCn + c] = v;
    }
    __syncthreads();
    if (tid < NCn) {
        logit_lds[tid] = red_lds[tid] + red_lds[NCn + tid] +
                         red_lds[2 * NCn + tid] + red_lds[3 * NCn + tid] + bo[tid];
    }
    __syncthreads();
    if (tid == 0) {
        float mx = logit_lds[0];
        for (int c = 1; c < NCn; ++c) mx = fmaxf(mx, logit_lds[c]);
        float e[NCn], sm = 0.0f;
        for (int c = 0; c < NCn; ++c) { e[c] = expf(logit_lds[c] - mx); sm += e[c]; }
        const float inv = 1.0f / sm;
        for (int c = 0; c < NCn; ++c) out[(size_t)b * NCn + c] = e[c] * inv;
    }
}

// ---- fallback (no workspace): raw f32 weights each step ----
__global__ __launch_bounds__(256)
void lstm_fallback(const float* __restrict__ X, const int* __restrict__ lengths,
                   const float* __restrict__ Wg, const float* __restrict__ bg,
                   const float* __restrict__ wdec, const float* __restrict__ bdec,
                   const float* __restrict__ Wo, const float* __restrict__ bo,
                   float* __restrict__ out)
{
    __shared__ __align__(16) float h_lds[Fn * Hn];
    __shared__ float c_lds[Hn];
    __shared__ int   m_lds[Ln];
    __shared__ float x_lds[Ln];
    __shared__ float d_lds[Ln];
    __shared__ float wd_lds[Fn], bd_lds[Fn];
    __shared__ float red_lds[4 * NCn];
    __shared__ float logit_lds[NCn];

    const int b   = blockIdx.x;
    const int tid = threadIdx.x;
    const int l   = tid & 63;
    const int w   = tid >> 6;
    const int q   = l & 3;
    const int u   = w * 16 + (l >> 2);

    const float* mrow = X + ((size_t)b * 4 + 1) * Ln;
    const float* xrow = X + ((size_t)b * 4 + 2) * Ln;
    const float* drow = X + ((size_t)b * 4 + 3) * Ln;

    for (int i = tid; i < Fn * Hn; i += 256) h_lds[i] = 0.0f;
    if (tid < Hn) c_lds[tid] = 0.0f;
    if (tid < Fn) { wd_lds[tid] = wdec[tid]; bd_lds[tid] = bdec[tid]; }
    for (int i = tid; i < Ln; i += 256) {
        m_lds[i] = (int)mrow[i];
        x_lds[i] = xrow[i];
        d_lds[i] = drow[i];
    }
    __syncthreads();

    int len = lengths[b];
    if (len > Ln) len = Ln;
    const int g_raw = q * 64 + u;

    for (int j = 0; j < len; ++j) {
        const int   mj = m_lds[j];
        const float xj = x_lds[j];
        const float dj = d_lds[j];
        const float dec = expf(-fmaxf(0.0f, fmaf(wd_lds[mj], dj, bd_lds[mj])));
        const float4* hp = (const float4*)(h_lds + mj * Hn);
        const float* row = Wg + ((size_t)mj * NGn + g_raw) * 65;
        float acc = fmaf(row[0], xj, bg[mj * NGn + g_raw]);
        float a0 = 0.f, a1 = 0.f, a2 = 0.f, a3 = 0.f;
#pragma unroll
        for (int k4 = 0; k4 < 16; ++k4) {
            float4 hv = hp[k4];
            a0 = fmaf(row[1 + 4*k4 + 0], hv.x, a0);
            a1 = fmaf(row[1 + 4*k4 + 1], hv.y, a1);
            a2 = fmaf(row[1 + 4*k4 + 2], hv.z, a2);
            a3 = fmaf(row[1 + 4*k4 + 3], hv.w, a3);
        }
        acc = fmaf(dec, (a0 + a1) + (a2 + a3), acc);
        const int base = l & ~3;
        const float gi = __shfl(acc, base + 0, 64);
        const float gf = __shfl(acc, base + 1, 64);
        const float go = __shfl(acc, base + 2, 64);
        const float gc = __shfl(acc, base + 3, 64);
        __syncthreads();
        const float c_new = fmaf(sigm_slow(gf), c_lds[u], sigm_slow(gi) * tanhf(gc));
        if (q == 0) {
            c_lds[u] = c_new;
            h_lds[mj * Hn + u] = sigm_slow(go) * tanhf(c_new);
        }
        __syncthreads();
    }

    float p[NCn];
#pragma unroll
    for (int c = 0; c < NCn; ++c) p[c] = 0.0f;
    for (int i = tid; i < IN_DIM; i += 256) {
        const float fv = (i < Hn) ? c_lds[i] : h_lds[i - Hn];
#pragma unroll
        for (int c = 0; c < NCn; ++c)
            p[c] = fmaf(Wo[(size_t)c * IN_DIM + i], fv, p[c]);
    }
#pragma unroll
    for (int c = 0; c < NCn; ++c) {
        float v = p[c];
#pragma unroll
        for (int off = 32; off > 0; off >>= 1) v += __shfl_down(v, off, 64);
        if (l == 0) red_lds[w * NCn + c] = v;
    }
    __syncthreads();
    if (tid < NCn) {
        logit_lds[tid] = red_lds[tid] + red_lds[NCn + tid] +
                         red_lds[2 * NCn + tid] + red_lds[3 * NCn + tid] + bo[tid];
    }
    __syncthreads();
    if (tid == 0) {
        float mx = logit_lds[0];
        for (int c = 1; c < NCn; ++c) mx = fmaxf(mx, logit_lds[c]);
        float e[NCn], s = 0.0f;
        for (int c = 0; c < NCn; ++c) { e[c] = expf(logit_lds[c] - mx); s += e[c]; }
        const float inv = 1.0f / s;
        for (int c = 0; c < NCn; ++c) out[(size_t)b * NCn + c] = e[c] * inv;
    }
}

extern "C" void kernel_launch(void* const* d_in, const int* in_sizes, int n_in,
                              void* d_out, int out_size, void* d_ws, size_t ws_size,
                              hipStream_t stream)
{
    const float* X      = (const float*)d_in[0];
    const int*   len    = (const int*)  d_in[1];
    const float* Wg     = (const float*)d_in[2];
    const float* bg     = (const float*)d_in[3];
    const float* wdec   = (const float*)d_in[4];
    const float* bdec   = (const float*)d_in[5];
    const float* Wo     = (const float*)d_in[6];
    const float* bo     = (const float*)d_in[7];
    float*       out    = (float*)d_out;

    const size_t gw_bytes  = (size_t)Fn * 2048 * sizeof(f16x8);   // 4,194,304
    const size_t gwb_bytes = (size_t)Fn * 512 * sizeof(float);    // 262,144
    const size_t need      = gw_bytes + gwb_bytes;

    if (ws_size >= need) {
        f16x8* Gw  = (f16x8*)d_ws;
        float* Gwb = (float*)((char*)d_ws + gw_bytes);
        prep_f16<<<Fn, 256, 0, stream>>>(Wg, bg, Gw, Gwb);
        lstm_pre<<<Bn, 256, 0, stream>>>(X, len, Gw, Gwb,
                                         wdec, bdec, Wo, bo, out);
    } else {
        lstm_fallback<<<Bn, 256, 0, stream>>>(X, len, Wg, bg,
                                              wdec, bdec, Wo, bo, out);
    }
}